// Round 1
// baseline (77.686 us; speedup 1.0000x reference)
//
#include <hip/hip_runtime.h>
#include <math.h>

// ROI max pooling, TF-style bin mapping (see reference):
//   hs = (int)(H*roi[0]) (truncate), sh = max((he-hs)/7, 1)
//   bin i<6 rows: [hs+i*sh, min(hs+(i+1)*sh, he));  bin 6: [hs+6*sh, he)
// Shapes fixed by setup_inputs(): fm (2,50,50,256) f32, rois (2,100,4) f32,
// out (2,100,7,7,256) f32.

#define PH 7
#define PW 7
#define B_ 2
#define H_ 50
#define W_ 50
#define C_ 256
#define R_ 100

__global__ __launch_bounds__(64) void ROIPoolingLayer_33071248179308_kernel(
    const float* __restrict__ fm,    // (B,H,W,C)
    const float* __restrict__ rois,  // (B,R,4)
    float* __restrict__ out)         // (B,R,PH,PW,C)
{
    const int block  = blockIdx.x;        // roiIdx*49 + cell
    const int cell   = block % (PH * PW);
    const int roiIdx = block / (PH * PW); // b*R + r
    const int b      = roiIdx / R_;
    const int i      = cell / PW;
    const int j      = cell % PW;

    const float* roi = rois + (size_t)roiIdx * 4;
    const float r0 = roi[0], r1 = roi[1], r2 = roi[2], r3 = roi[3];

    // Truncating casts match jnp astype(int32) for non-negative values.
    const int hs = (int)((float)H_ * r0);
    const int ws = (int)((float)W_ * r1);
    const int he = (int)((float)H_ * r2);
    const int we = (int)((float)W_ * r3);
    const int sh = max((he - hs) / PH, 1);
    const int sw = max((we - ws) / PW, 1);

    const int y0 = hs + i * sh;
    const int y1 = (i == PH - 1) ? he : min(hs + (i + 1) * sh, he);
    const int x0 = ws + j * sw;
    const int x1 = (j == PW - 1) ? we : min(ws + (j + 1) * sw, we);

    const int c = threadIdx.x * 4;    // 64 lanes x 4 channels = 256 = C_

    float4 m = make_float4(-INFINITY, -INFINITY, -INFINITY, -INFINITY);
    const float* fmb = fm + (size_t)b * H_ * W_ * C_ + c;
    for (int y = y0; y < y1; ++y) {
        const float* rowp = fmb + (size_t)y * W_ * C_;
        for (int x = x0; x < x1; ++x) {
            const float4 v = *(const float4*)(rowp + (size_t)x * C_);
            m.x = fmaxf(m.x, v.x);
            m.y = fmaxf(m.y, v.y);
            m.z = fmaxf(m.z, v.z);
            m.w = fmaxf(m.w, v.w);
        }
    }
    *(float4*)(out + (size_t)block * C_ + c) = m;
}

extern "C" void kernel_launch(void* const* d_in, const int* in_sizes, int n_in,
                              void* d_out, int out_size, void* d_ws, size_t ws_size,
                              hipStream_t stream) {
    const float* fm   = (const float*)d_in[0];
    const float* rois = (const float*)d_in[1];
    float* out        = (float*)d_out;

    const int nblocks = B_ * R_ * PH * PW;  // 9800
    ROIPoolingLayer_33071248179308_kernel<<<nblocks, 64, 0, stream>>>(fm, rois, out);
}

// Round 2
// 68.432 us; speedup vs baseline: 1.1352x; 1.1352x over previous
//
#include <hip/hip_runtime.h>
#include <math.h>

// ROI max pooling, TF-style bin mapping (see reference):
//   hs = (int)(H*roi[0]) (truncate), sh = max((he-hs)/7, 1)
//   bin i<6 rows: [hs+i*sh, min(hs+(i+1)*sh, he));  bin 6: [hs+6*sh, he)
// Shapes fixed by setup_inputs(): fm (2,50,50,256) f32, rois (2,100,4) f32,
// out (2,100,7,7,256) f32.
//
// R2: latency-bound fix — flatten each bin's (bh x bw) positions into a
// stream consumed in chunks of 8 with 8 outstanding global loads per
// waitcnt (explicit memory-level parallelism). Addresses advance
// incrementally (no divides in the hot loop). One wave per output cell,
// lane c holds channels 4c..4c+3 (64 lanes x float4 = 256 ch, 1 KiB/wave
// per position = ideal coalescing).

#define PH 7
#define PW 7
#define B_ 2
#define H_ 50
#define W_ 50
#define C_ 256
#define R_ 100

#define CHUNK 8

__global__ __launch_bounds__(64) void ROIPoolingLayer_33071248179308_kernel(
    const float* __restrict__ fm,    // (B,H,W,C)
    const float* __restrict__ rois,  // (B,R,4)
    float* __restrict__ out)         // (B,R,PH,PW,C)
{
    const int block  = blockIdx.x;        // roiIdx*49 + cell
    const int cell   = block % (PH * PW);
    const int roiIdx = block / (PH * PW); // b*R + r
    const int b      = roiIdx / R_;
    const int i      = cell / PW;
    const int j      = cell % PW;

    // One 16B load for the whole ROI descriptor (wave-uniform address).
    const float4 roi = *(const float4*)(rois + (size_t)roiIdx * 4);

    // Truncating casts match jnp astype(int32) for non-negative values.
    const int hs = (int)((float)H_ * roi.x);
    const int ws = (int)((float)W_ * roi.y);
    const int he = (int)((float)H_ * roi.z);
    const int we = (int)((float)W_ * roi.w);
    const int sh = max((he - hs) / PH, 1);
    const int sw = max((we - ws) / PW, 1);

    const int y0 = hs + i * sh;
    const int y1 = (i == PH - 1) ? he : min(hs + (i + 1) * sh, he);
    const int x0 = ws + j * sw;
    const int x1 = (j == PW - 1) ? we : min(ws + (j + 1) * sw, we);

    const int bw = x1 - x0;
    const int bh = y1 - y0;
    int n = (bw > 0 && bh > 0) ? bh * bw : 0;

    const int c = threadIdx.x * 4;    // 64 lanes x 4 channels = 256 = C_

    float4 m = make_float4(-INFINITY, -INFINITY, -INFINITY, -INFINITY);

    // Incremental position walker over the bin, row-major.
    int x = x0;
    const float* p = fm + ((size_t)b * H_ * W_ + (size_t)y0 * W_ + x0) * C_ + c;
    const ptrdiff_t row_skip = (ptrdiff_t)(W_ - bw) * C_;  // jump to next row start

    while (n > 0) {
        const int take = (n < CHUNK) ? n : CHUNK;
        float4 buf[CHUNK];
#pragma unroll
        for (int t = 0; t < CHUNK; ++t) {
            if (t < take) {
                buf[t] = *(const float4*)p;   // issued back-to-back: 8 in flight
                p += C_;
                if (++x == x1) { x = x0; p += row_skip; }
            }
        }
#pragma unroll
        for (int t = 0; t < CHUNK; ++t) {
            if (t < take) {
                m.x = fmaxf(m.x, buf[t].x);
                m.y = fmaxf(m.y, buf[t].y);
                m.z = fmaxf(m.z, buf[t].z);
                m.w = fmaxf(m.w, buf[t].w);
            }
        }
        n -= take;
    }

    *(float4*)(out + (size_t)block * C_ + c) = m;
}

extern "C" void kernel_launch(void* const* d_in, const int* in_sizes, int n_in,
                              void* d_out, int out_size, void* d_ws, size_t ws_size,
                              hipStream_t stream) {
    const float* fm   = (const float*)d_in[0];
    const float* rois = (const float*)d_in[1];
    float* out        = (float*)d_out;

    const int nblocks = B_ * R_ * PH * PW;  // 9800
    ROIPoolingLayer_33071248179308_kernel<<<nblocks, 64, 0, stream>>>(fm, rois, out);
}